// Round 3
// baseline (163.974 us; speedup 1.0000x reference)
//
#include <hip/hip_runtime.h>
#include <hip/hip_bf16.h>

#define EMBED 1024
#define WINDOW 512
#define NROWS 16384  // 4 * 4096

typedef __attribute__((ext_vector_type(4))) float f32x4;
typedef __bf16 bf16x8 __attribute__((ext_vector_type(8)));

#define GLDS(g, l)                                                        \
  __builtin_amdgcn_global_load_lds(                                       \
      (const __attribute__((address_space(1))) void*)(const void*)(g),    \
      (__attribute__((address_space(3))) void*)(void*)(l), 16, 0, 0)

// ---------------- prep: fp32 -> bf16 cast, 8 elems/thread ----------------
__global__ __launch_bounds__(256) void cast_bf16_kernel(
    const float* __restrict__ in, __bf16* __restrict__ out, int n8) {
  int i = blockIdx.x * blockDim.x + threadIdx.x;
  if (i >= n8) return;
  const f32x4* p = (const f32x4*)(in + (size_t)i * 8);
  f32x4 a = p[0], b = p[1];
  bf16x8 o = {(__bf16)a[0], (__bf16)a[1], (__bf16)a[2], (__bf16)a[3],
              (__bf16)b[0], (__bf16)b[1], (__bf16)b[2], (__bf16)b[3]};
  *(bf16x8*)(out + (size_t)i * 8) = o;
}

// ---------------- prep: MB [512][1024] fp32 -> MB^T [1024][512] bf16 ------
__global__ __launch_bounds__(256) void transpose_mb_kernel(
    const float* __restrict__ mb, __bf16* __restrict__ mbt) {
  int idx = blockIdx.x * blockDim.x + threadIdx.x;  // over 512*1024
  int w = idx >> 10, d = idx & 1023;
  mbt[(size_t)d * WINDOW + w] = (__bf16)mb[idx];
}

// ---------------- GEMM1: S1[16384x512] = xb @ mbb^T, K=1024 --------------
// 128x128 tile, 256 threads (4 waves 2x2), BK=32, global_load_lds staging.
__global__ __launch_bounds__(256) void gemm_scores_kernel(
    const __bf16* __restrict__ xb, const __bf16* __restrict__ mbb,
    __bf16* __restrict__ s1) {
  __shared__ __bf16 Ash[128 * 32];
  __shared__ __bf16 Bsh[128 * 32];
  const int lane = threadIdx.x & 63;
  const int wave = threadIdx.x >> 6;
  const int bm = blockIdx.x >> 2;      // 128 row-blocks
  const int bn = blockIdx.x & 3;       // 4 col-blocks
  const int row0 = bm * 128;
  const int col0 = bn * 128;
  const int wr = (wave >> 1) * 64;
  const int wc = (wave & 1) * 64;
  const int fr = lane & 15;
  const int fq = lane >> 4;
  const int sub = lane >> 2;           // staging: row within 16
  const int ke = (lane & 3) * 8;       // staging: k elem base

  f32x4 acc[4][4];
#pragma unroll
  for (int m = 0; m < 4; ++m)
#pragma unroll
    for (int n = 0; n < 4; ++n) acc[m][n] = (f32x4){0.f, 0.f, 0.f, 0.f};

  for (int kt = 0; kt < 32; ++kt) {
    const int k0 = kt * 32;
#pragma unroll
    for (int i = 0; i < 2; ++i) {
      const int rb = wave * 32 + i * 16;  // row-chunk base (uniform per wave)
      GLDS(xb + (size_t)(row0 + rb + sub) * EMBED + k0 + ke, &Ash[rb * 32]);
      GLDS(mbb + (size_t)(col0 + rb + sub) * EMBED + k0 + ke, &Bsh[rb * 32]);
    }
    __syncthreads();
    bf16x8 ar[4], br[4];
#pragma unroll
    for (int m = 0; m < 4; ++m)
      ar[m] = *(const bf16x8*)&Ash[(wr + m * 16 + fr) * 32 + fq * 8];
#pragma unroll
    for (int n = 0; n < 4; ++n)
      br[n] = *(const bf16x8*)&Bsh[(wc + n * 16 + fr) * 32 + fq * 8];
#pragma unroll
    for (int m = 0; m < 4; ++m)
#pragma unroll
      for (int n = 0; n < 4; ++n)
        acc[m][n] =
            __builtin_amdgcn_mfma_f32_16x16x32_bf16(ar[m], br[n], acc[m][n], 0, 0, 0);
    __syncthreads();
  }

#pragma unroll
  for (int m = 0; m < 4; ++m)
#pragma unroll
    for (int n = 0; n < 4; ++n) {
      const int col = col0 + wc + n * 16 + fr;
#pragma unroll
      for (int j = 0; j < 4; ++j) {
        const int row = row0 + wr + m * 16 + fq * 4 + j;
        s1[(size_t)row * WINDOW + col] = (__bf16)acc[m][n][j];
      }
    }
}

// ---------------- softmax in-place on S1 rows (512 wide) -----------------
__global__ __launch_bounds__(256) void softmax_kernel(__bf16* __restrict__ s1) {
  const int row = blockIdx.x * 4 + (threadIdx.x >> 6);
  const int lane = threadIdx.x & 63;
  __bf16* p = s1 + (size_t)row * WINDOW + lane * 8;
  bf16x8 v = *(const bf16x8*)p;
  float f[8];
  float mx = -1e30f;
#pragma unroll
  for (int j = 0; j < 8; ++j) {
    f[j] = (float)v[j] * 0.03125f;  // 1/sqrt(1024)
    mx = fmaxf(mx, f[j]);
  }
#pragma unroll
  for (int off = 1; off < 64; off <<= 1) mx = fmaxf(mx, __shfl_xor(mx, off));
  float s = 0.f;
#pragma unroll
  for (int j = 0; j < 8; ++j) {
    f[j] = __expf(f[j] - mx);
    s += f[j];
  }
#pragma unroll
  for (int off = 1; off < 64; off <<= 1) s += __shfl_xor(s, off);
  const float inv = 1.0f / s;
  bf16x8 o;
#pragma unroll
  for (int j = 0; j < 8; ++j) o[j] = (__bf16)(f[j] * inv);
  *(bf16x8*)p = o;
}

// ---------------- 256x256 tile GEMM, 8 waves, BK=64, dbuf LDS ------------
// C[row][col] = sum_k A[row][k] * B[col][k]   (B is K-contiguous, LDB stride)
// EPI==0: out[row*1024+col]  = acc               (retrieved, f32)
// EPI==1: g = sigmoid(acc + gb[col]);
//         out[row*1024+col] = g*xb + (1-g)*out[row*1024+col]
template <int KT, int LDA_, int LDB_, int EPI>
__global__ __launch_bounds__(512, 2) void gemm256_kernel(
    const __bf16* __restrict__ A, const __bf16* __restrict__ B,
    const float* __restrict__ gb, const __bf16* __restrict__ xb,
    float* __restrict__ out) {
  __shared__ __align__(16) __bf16 ldsA[2][256 * 64];
  __shared__ __align__(16) __bf16 ldsB[2][256 * 64];
  const int tid = threadIdx.x;
  const int lane = tid & 63;
  const int wave = tid >> 6;

  // XCD-grouped mapping: same-bm blocks land on the same XCD (bid%8).
  const int bid = blockIdx.x;          // 256 blocks
  const int xcd = bid & 7;
  const int idx = bid >> 3;            // 0..31
  const int bm = xcd * 8 + (idx >> 2); // 0..63
  const int bn = idx & 3;              // 0..3
  const int row0 = bm * 256;
  const int col0 = bn * 256;
  const int warp_m = wave >> 2;        // 0..1  -> 128 rows
  const int warp_n = wave & 3;         // 0..3  -> 64 cols

  // staging geometry: per wave 4 chunks of 8 rows x 64 cols per matrix.
  // LDS dest is linear; global source col-granule is pre-swizzled so that
  // a swizzled ds_read (granule ^= row&7) reads the logical data. (involution)
  const int srow = lane >> 3;                 // 0..7
  const int sgc = (lane & 7) ^ srow;          // swizzled source granule
  const __bf16* aSrc = A + (size_t)(row0 + wave * 32 + srow) * LDA_ + sgc * 8;
  const __bf16* bSrc = B + (size_t)(col0 + wave * 32 + srow) * LDB_ + sgc * 8;

#define STAGE256(buf, kt)                                                     \
  {                                                                           \
    const int k0_ = (kt) * 64;                                                \
    _Pragma("unroll") for (int c = 0; c < 4; ++c)                             \
        GLDS(aSrc + (size_t)c * 8 * LDA_ + k0_,                               \
             &ldsA[buf][(wave * 32 + c * 8) * 64]);                           \
    _Pragma("unroll") for (int c = 0; c < 4; ++c)                             \
        GLDS(bSrc + (size_t)c * 8 * LDB_ + k0_,                               \
             &ldsB[buf][(wave * 32 + c * 8) * 64]);                           \
  }

  const int fr = lane & 15;
  const int fq = lane >> 4;
  const int swz = fr & 7;

  f32x4 acc[8][4];
#pragma unroll
  for (int m = 0; m < 8; ++m)
#pragma unroll
    for (int n = 0; n < 4; ++n) acc[m][n] = (f32x4){0.f, 0.f, 0.f, 0.f};

  STAGE256(0, 0);
  int cur = 0;
  for (int t = 0; t < KT; ++t) {
    if (t + 1 < KT) {
      STAGE256(cur ^ 1, t + 1);
      asm volatile("s_waitcnt vmcnt(8)" ::: "memory");  // my tile-t loads done
    } else {
      asm volatile("s_waitcnt vmcnt(0)" ::: "memory");
    }
    __builtin_amdgcn_s_barrier();          // everyone's tile-t loads done
    asm volatile("" ::: "memory");
#pragma unroll
    for (int kk = 0; kk < 2; ++kk) {
      const int pg = ((kk * 4 + fq) ^ swz) * 8;  // swizzled granule (elems)
      bf16x8 af[8], bfr[4];
#pragma unroll
      for (int m = 0; m < 8; ++m)
        af[m] = *(const bf16x8*)&ldsA[cur][(warp_m * 128 + m * 16 + fr) * 64 + pg];
#pragma unroll
      for (int n = 0; n < 4; ++n)
        bfr[n] = *(const bf16x8*)&ldsB[cur][(warp_n * 64 + n * 16 + fr) * 64 + pg];
      __builtin_amdgcn_s_setprio(1);
#pragma unroll
      for (int m = 0; m < 8; ++m)
#pragma unroll
        for (int n = 0; n < 4; ++n)
          acc[m][n] = __builtin_amdgcn_mfma_f32_16x16x32_bf16(af[m], bfr[n],
                                                              acc[m][n], 0, 0, 0);
      __builtin_amdgcn_s_setprio(0);
    }
    __builtin_amdgcn_s_barrier();          // all reads done before overwrite
    asm volatile("" ::: "memory");
    cur ^= 1;
  }
#undef STAGE256

#pragma unroll
  for (int n = 0; n < 4; ++n) {
    const int col = col0 + warp_n * 64 + n * 16 + fr;
    const float bias = (EPI == 1) ? gb[col] : 0.f;
#pragma unroll
    for (int m = 0; m < 8; ++m) {
#pragma unroll
      for (int j = 0; j < 4; ++j) {
        const int row = row0 + warp_m * 128 + m * 16 + fq * 4 + j;
        const size_t o = (size_t)row * EMBED + col;
        if (EPI == 0) {
          out[o] = acc[m][n][j];
        } else {
          const float g = 1.0f / (1.0f + __expf(-(acc[m][n][j] + bias)));
          const float xv = (float)xb[o];
          out[o] = g * xv + (1.0f - g) * out[o];
        }
      }
    }
  }
}

extern "C" void kernel_launch(void* const* d_in, const int* in_sizes, int n_in,
                              void* d_out, int out_size, void* d_ws,
                              size_t ws_size, hipStream_t stream) {
  const float* x = (const float*)d_in[0];
  const float* mb = (const float*)d_in[1];
  const float* gw = (const float*)d_in[2];
  const float* gb = (const float*)d_in[3];
  float* out = (float*)d_out;

  char* ws = (char*)d_ws;
  __bf16* xb = (__bf16*)(ws);                   // 16384*1024*2 = 33,554,432
  __bf16* mbb = (__bf16*)(ws + 33554432);       // 512*1024*2  =  1,048,576
  __bf16* mbt = (__bf16*)(ws + 34603008);       // 1024*512*2  =  1,048,576
  __bf16* gwb = (__bf16*)(ws + 35651584);       // 1024*1024*2 =  2,097,152
  __bf16* s1 = (__bf16*)(ws + 37748736);        // 16384*512*2 = 16,777,216
  // total 54,525,952 bytes

  cast_bf16_kernel<<<8192, 256, 0, stream>>>(x, xb, 2097152);
  cast_bf16_kernel<<<256, 256, 0, stream>>>(mb, mbb, 65536);
  cast_bf16_kernel<<<512, 256, 0, stream>>>(gw, gwb, 131072);
  transpose_mb_kernel<<<2048, 256, 0, stream>>>(mb, mbt);
  gemm_scores_kernel<<<512, 256, 0, stream>>>(xb, mbb, s1);
  softmax_kernel<<<4096, 256, 0, stream>>>(s1);
  // retrieved = softmax(S1) @ MB  -> f32 into d_out
  gemm256_kernel<8, WINDOW, WINDOW, 0><<<256, 512, 0, stream>>>(
      s1, mbt, gb, xb, out);
  // gate = sigmoid(xb @ gw^T + gb); out = g*x + (1-g)*retrieved
  gemm256_kernel<16, EMBED, EMBED, 1><<<256, 512, 0, stream>>>(
      xb, gwb, gb, xb, out);
}

// Round 4
// 144.927 us; speedup vs baseline: 1.1314x; 1.1314x over previous
//
#include <hip/hip_runtime.h>
#include <hip/hip_bf16.h>

#define EMBED 1024
#define WINDOW 512
#define NROWS 16384  // 4 * 4096

typedef __attribute__((ext_vector_type(4))) float f32x4;
typedef __bf16 bf16x8 __attribute__((ext_vector_type(8)));

#define GLDS(g, l)                                                        \
  __builtin_amdgcn_global_load_lds(                                       \
      (const __attribute__((address_space(1))) void*)(const void*)(g),    \
      (__attribute__((address_space(3))) void*)(void*)(l), 16, 0, 0)

// ---------------- prep: fp32 -> bf16 cast, 8 elems/thread ----------------
__global__ __launch_bounds__(256) void cast_bf16_kernel(
    const float* __restrict__ in, __bf16* __restrict__ out, int n8) {
  int i = blockIdx.x * blockDim.x + threadIdx.x;
  if (i >= n8) return;
  const f32x4* p = (const f32x4*)(in + (size_t)i * 8);
  f32x4 a = p[0], b = p[1];
  bf16x8 o = {(__bf16)a[0], (__bf16)a[1], (__bf16)a[2], (__bf16)a[3],
              (__bf16)b[0], (__bf16)b[1], (__bf16)b[2], (__bf16)b[3]};
  *(bf16x8*)(out + (size_t)i * 8) = o;
}

// ---------------- prep: MB [512][1024] fp32 -> MB^T [1024][512] bf16 ------
__global__ __launch_bounds__(256) void transpose_mb_kernel(
    const float* __restrict__ mb, __bf16* __restrict__ mbt) {
  int idx = blockIdx.x * blockDim.x + threadIdx.x;  // over 512*1024
  int w = idx >> 10, d = idx & 1023;
  mbt[(size_t)d * WINDOW + w] = (__bf16)mb[idx];
}

// ---------------- GEMM1: S1[16384x512] = xb @ mbb^T, K=1024 --------------
// 128x128 tile, 256 threads (4 waves 2x2), BK=32, global_load_lds staging.
__global__ __launch_bounds__(256) void gemm_scores_kernel(
    const __bf16* __restrict__ xb, const __bf16* __restrict__ mbb,
    __bf16* __restrict__ s1) {
  __shared__ __bf16 Ash[128 * 32];
  __shared__ __bf16 Bsh[128 * 32];
  const int lane = threadIdx.x & 63;
  const int wave = threadIdx.x >> 6;
  const int bm = blockIdx.x >> 2;      // 128 row-blocks
  const int bn = blockIdx.x & 3;       // 4 col-blocks
  const int row0 = bm * 128;
  const int col0 = bn * 128;
  const int wr = (wave >> 1) * 64;
  const int wc = (wave & 1) * 64;
  const int fr = lane & 15;
  const int fq = lane >> 4;
  const int sub = lane >> 2;           // staging: row within 16
  const int ke = (lane & 3) * 8;       // staging: k elem base

  f32x4 acc[4][4];
#pragma unroll
  for (int m = 0; m < 4; ++m)
#pragma unroll
    for (int n = 0; n < 4; ++n) acc[m][n] = (f32x4){0.f, 0.f, 0.f, 0.f};

  for (int kt = 0; kt < 32; ++kt) {
    const int k0 = kt * 32;
#pragma unroll
    for (int i = 0; i < 2; ++i) {
      const int rb = wave * 32 + i * 16;  // row-chunk base (uniform per wave)
      GLDS(xb + (size_t)(row0 + rb + sub) * EMBED + k0 + ke, &Ash[rb * 32]);
      GLDS(mbb + (size_t)(col0 + rb + sub) * EMBED + k0 + ke, &Bsh[rb * 32]);
    }
    __syncthreads();
    bf16x8 ar[4], br[4];
#pragma unroll
    for (int m = 0; m < 4; ++m)
      ar[m] = *(const bf16x8*)&Ash[(wr + m * 16 + fr) * 32 + fq * 8];
#pragma unroll
    for (int n = 0; n < 4; ++n)
      br[n] = *(const bf16x8*)&Bsh[(wc + n * 16 + fr) * 32 + fq * 8];
#pragma unroll
    for (int m = 0; m < 4; ++m)
#pragma unroll
      for (int n = 0; n < 4; ++n)
        acc[m][n] =
            __builtin_amdgcn_mfma_f32_16x16x32_bf16(ar[m], br[n], acc[m][n], 0, 0, 0);
    __syncthreads();
  }

#pragma unroll
  for (int m = 0; m < 4; ++m)
#pragma unroll
    for (int n = 0; n < 4; ++n) {
      const int col = col0 + wc + n * 16 + fr;
#pragma unroll
      for (int j = 0; j < 4; ++j) {
        const int row = row0 + wr + m * 16 + fq * 4 + j;
        s1[(size_t)row * WINDOW + col] = (__bf16)acc[m][n][j];
      }
    }
}

// ---------------- softmax in-place on S1 rows (512 wide) -----------------
__global__ __launch_bounds__(256) void softmax_kernel(__bf16* __restrict__ s1) {
  const int row = blockIdx.x * 4 + (threadIdx.x >> 6);
  const int lane = threadIdx.x & 63;
  __bf16* p = s1 + (size_t)row * WINDOW + lane * 8;
  bf16x8 v = *(const bf16x8*)p;
  float f[8];
  float mx = -1e30f;
#pragma unroll
  for (int j = 0; j < 8; ++j) {
    f[j] = (float)v[j] * 0.03125f;  // 1/sqrt(1024)
    mx = fmaxf(mx, f[j]);
  }
#pragma unroll
  for (int off = 1; off < 64; off <<= 1) mx = fmaxf(mx, __shfl_xor(mx, off));
  float s = 0.f;
#pragma unroll
  for (int j = 0; j < 8; ++j) {
    f[j] = __expf(f[j] - mx);
    s += f[j];
  }
#pragma unroll
  for (int off = 1; off < 64; off <<= 1) s += __shfl_xor(s, off);
  const float inv = 1.0f / s;
  bf16x8 o;
#pragma unroll
  for (int j = 0; j < 8; ++j) o[j] = (__bf16)(f[j] * inv);
  *(bf16x8*)p = o;
}

// ---------------- fused dual GEMM + blend, deep-pipelined ----------------
// BM=256, BN=128, BK=64, 8 waves (4M x 2N), 64x64 per wave per GEMM.
// Virtual K-loop: vt 0..7  -> retrieved += s1_tile @ mbt_tile   (K=512)
//                 vt 8..23 -> gate_pre += xb_tile @ gwb_tile    (K=1024)
// Triple-buffered LDS, 2-tile lookahead, counted vmcnt(6), 1 barrier/tile.
// Epilogue: g = sigmoid(accg + gb); out = g*x + (1-g)*accr.
__global__ __launch_bounds__(512, 2) void dual_fused_kernel(
    const __bf16* __restrict__ s1, const __bf16* __restrict__ xb,
    const __bf16* __restrict__ mbt, const __bf16* __restrict__ gwb,
    const float* __restrict__ gb, float* __restrict__ out) {
  __shared__ __align__(16) __bf16 ldsA[3][256 * 64];  // 96 KB
  __shared__ __align__(16) __bf16 ldsB[3][128 * 64];  // 48 KB
  const int tid = threadIdx.x;
  const int lane = tid & 63;
  const int wave = tid >> 6;

  // XCD-grouped bijection: 8 blocks sharing bm (the A panel) -> same XCD.
  const int bid = blockIdx.x;               // 512 blocks
  const int bm = (bid & 7) * 8 + ((bid >> 3) & 7);  // 0..63
  const int bn = bid >> 6;                  // 0..7
  const int row0 = bm * 256;
  const int col0 = bn * 128;
  const int warp_m = wave >> 1;             // 0..3 -> 64-row slice
  const int warp_n = wave & 1;              // 0..1 -> 64-col slice

  // staging: wave stages A rows [wave*32, +32) (4 glds x 8 rows) and
  // B rows [wave*16, +16) (2 glds). LDS dest linear; source granule
  // pre-swizzled (g ^ row&7) so the swizzled ds_read is the involution.
  const int srow = lane >> 3;               // 0..7
  const int sgc = (lane & 7) ^ srow;        // swizzled source granule
  const int wv32 = wave * 32;
  const int wv16 = wave * 16;

  const __bf16* aR = s1 + (size_t)(row0 + wv32 + srow) * WINDOW + sgc * 8;
  const __bf16* bR = mbt + (size_t)(col0 + wv16 + srow) * WINDOW + sgc * 8;
  const __bf16* aG = xb + (size_t)(row0 + wv32 + srow) * EMBED + sgc * 8;
  const __bf16* bG = gwb + (size_t)(col0 + wv16 + srow) * EMBED + sgc * 8;

#define STAGE_D(vt, buf)                                                      \
  {                                                                           \
    if ((vt) < 8) {                                                           \
      const int k0_ = (vt) * 64;                                              \
      _Pragma("unroll") for (int c = 0; c < 4; ++c)                           \
          GLDS(aR + (size_t)c * 8 * WINDOW + k0_,                             \
               &ldsA[buf][(wv32 + c * 8) * 64]);                              \
      _Pragma("unroll") for (int c = 0; c < 2; ++c)                           \
          GLDS(bR + (size_t)c * 8 * WINDOW + k0_,                             \
               &ldsB[buf][(wv16 + c * 8) * 64]);                              \
    } else {                                                                  \
      const int k0_ = ((vt) - 8) * 64;                                        \
      _Pragma("unroll") for (int c = 0; c < 4; ++c)                           \
          GLDS(aG + (size_t)c * 8 * EMBED + k0_,                              \
               &ldsA[buf][(wv32 + c * 8) * 64]);                              \
      _Pragma("unroll") for (int c = 0; c < 2; ++c)                           \
          GLDS(bG + (size_t)c * 8 * EMBED + k0_,                              \
               &ldsB[buf][(wv16 + c * 8) * 64]);                              \
    }                                                                         \
  }

  const int fr = lane & 15;
  const int fq = lane >> 4;

  f32x4 accr[4][4], accg[4][4];
#pragma unroll
  for (int m = 0; m < 4; ++m)
#pragma unroll
    for (int n = 0; n < 4; ++n) {
      accr[m][n] = (f32x4){0.f, 0.f, 0.f, 0.f};
      accg[m][n] = (f32x4){0.f, 0.f, 0.f, 0.f};
    }

  STAGE_D(0, 0);
  STAGE_D(1, 1);

  for (int vt = 0; vt < 24; ++vt) {
    // wait for THIS tile's loads (issued 2 iterations ago); keep vt+1's
    // 6 loads in flight. Never drain to 0 mid-loop.
    if (vt + 1 < 24) {
      asm volatile("s_waitcnt vmcnt(6)" ::: "memory");
    } else {
      asm volatile("s_waitcnt vmcnt(0)" ::: "memory");
    }
    __builtin_amdgcn_s_barrier();  // all waves' tile-vt loads are in LDS
    asm volatile("" ::: "memory");
    if (vt + 2 < 24) {
      const int nb = (vt + 2) % 3;  // overwrites buffer consumed at vt-1
      STAGE_D(vt + 2, nb);
    }
    const int cb = vt % 3;
    const __bf16* As = &ldsA[cb][(warp_m * 64 + fr) * 64];
    const __bf16* Bs = &ldsB[cb][(warp_n * 64 + fr) * 64];
#pragma unroll
    for (int kk = 0; kk < 2; ++kk) {
      const int pg = ((kk * 4 + fq) ^ (fr & 7)) * 8;  // swizzled granule
      bf16x8 af[4], bf_[4];
#pragma unroll
      for (int m = 0; m < 4; ++m)
        af[m] = *(const bf16x8*)(As + m * 16 * 64 + pg);
#pragma unroll
      for (int n = 0; n < 4; ++n)
        bf_[n] = *(const bf16x8*)(Bs + n * 16 * 64 + pg);
      __builtin_amdgcn_s_setprio(1);
      if (vt < 8) {
#pragma unroll
        for (int m = 0; m < 4; ++m)
#pragma unroll
          for (int n = 0; n < 4; ++n)
            accr[m][n] = __builtin_amdgcn_mfma_f32_16x16x32_bf16(
                af[m], bf_[n], accr[m][n], 0, 0, 0);
      } else {
#pragma unroll
        for (int m = 0; m < 4; ++m)
#pragma unroll
          for (int n = 0; n < 4; ++n)
            accg[m][n] = __builtin_amdgcn_mfma_f32_16x16x32_bf16(
                af[m], bf_[n], accg[m][n], 0, 0, 0);
      }
      __builtin_amdgcn_s_setprio(0);
    }
  }
#undef STAGE_D

  // epilogue: blend
#pragma unroll
  for (int n = 0; n < 4; ++n) {
    const int col = col0 + warp_n * 64 + n * 16 + fr;
    const float bias = gb[col];
#pragma unroll
    for (int m = 0; m < 4; ++m) {
#pragma unroll
      for (int j = 0; j < 4; ++j) {
        const int row = row0 + warp_m * 64 + m * 16 + fq * 4 + j;
        const size_t o = (size_t)row * EMBED + col;
        const float g = 1.0f / (1.0f + __expf(-(accg[m][n][j] + bias)));
        const float xv = (float)xb[o];
        out[o] = g * xv + (1.0f - g) * accr[m][n][j];
      }
    }
  }
}

extern "C" void kernel_launch(void* const* d_in, const int* in_sizes, int n_in,
                              void* d_out, int out_size, void* d_ws,
                              size_t ws_size, hipStream_t stream) {
  const float* x = (const float*)d_in[0];
  const float* mb = (const float*)d_in[1];
  const float* gw = (const float*)d_in[2];
  const float* gb = (const float*)d_in[3];
  float* out = (float*)d_out;

  char* ws = (char*)d_ws;
  __bf16* xb = (__bf16*)(ws);                   // 16384*1024*2 = 33,554,432
  __bf16* mbb = (__bf16*)(ws + 33554432);       // 512*1024*2  =  1,048,576
  __bf16* mbt = (__bf16*)(ws + 34603008);       // 1024*512*2  =  1,048,576
  __bf16* gwb = (__bf16*)(ws + 35651584);       // 1024*1024*2 =  2,097,152
  __bf16* s1 = (__bf16*)(ws + 37748736);        // 16384*512*2 = 16,777,216
  // total 54,525,952 bytes

  cast_bf16_kernel<<<8192, 256, 0, stream>>>(x, xb, 2097152);
  cast_bf16_kernel<<<256, 256, 0, stream>>>(mb, mbb, 65536);
  cast_bf16_kernel<<<512, 256, 0, stream>>>(gw, gwb, 131072);
  transpose_mb_kernel<<<2048, 256, 0, stream>>>(mb, mbt);
  gemm_scores_kernel<<<512, 256, 0, stream>>>(xb, mbb, s1);
  softmax_kernel<<<4096, 256, 0, stream>>>(s1);
  dual_fused_kernel<<<512, 512, 0, stream>>>(s1, xb, mbt, gwb, gb, out);
}

// Round 5
// 125.539 us; speedup vs baseline: 1.3062x; 1.1544x over previous
//
#include <hip/hip_runtime.h>
#include <hip/hip_bf16.h>

#define EMBED 1024
#define WINDOW 512
#define NROWS 16384  // 4 * 4096

typedef __attribute__((ext_vector_type(4))) float f32x4;
typedef __bf16 bf16x8 __attribute__((ext_vector_type(8)));

#define GLDS(g, l)                                                        \
  __builtin_amdgcn_global_load_lds(                                       \
      (const __attribute__((address_space(1))) void*)(const void*)(g),    \
      (__attribute__((address_space(3))) void*)(void*)(l), 16, 0, 0)

// ---------------- prep: fp32 -> bf16 cast, 8 elems/thread ----------------
__global__ __launch_bounds__(256) void cast_bf16_kernel(
    const float* __restrict__ in, __bf16* __restrict__ out, int n8) {
  int i = blockIdx.x * blockDim.x + threadIdx.x;
  if (i >= n8) return;
  const f32x4* p = (const f32x4*)(in + (size_t)i * 8);
  f32x4 a = p[0], b = p[1];
  bf16x8 o = {(__bf16)a[0], (__bf16)a[1], (__bf16)a[2], (__bf16)a[3],
              (__bf16)b[0], (__bf16)b[1], (__bf16)b[2], (__bf16)b[3]};
  *(bf16x8*)(out + (size_t)i * 8) = o;
}

// ---------------- prep: MB [512][1024] fp32 -> MB^T [1024][512] bf16 ------
__global__ __launch_bounds__(256) void transpose_mb_kernel(
    const float* __restrict__ mb, __bf16* __restrict__ mbt) {
  int idx = blockIdx.x * blockDim.x + threadIdx.x;  // over 512*1024
  int w = idx >> 10, d = idx & 1023;
  mbt[(size_t)d * WINDOW + w] = (__bf16)mb[idx];
}

// ---------------- softmax in-place on S1 rows (512 wide) -----------------
__global__ __launch_bounds__(256) void softmax_kernel(__bf16* __restrict__ s1) {
  const int row = blockIdx.x * 4 + (threadIdx.x >> 6);
  const int lane = threadIdx.x & 63;
  __bf16* p = s1 + (size_t)row * WINDOW + lane * 8;
  bf16x8 v = *(const bf16x8*)p;
  float f[8];
  float mx = -1e30f;
#pragma unroll
  for (int j = 0; j < 8; ++j) {
    f[j] = (float)v[j] * 0.03125f;  // 1/sqrt(1024)
    mx = fmaxf(mx, f[j]);
  }
#pragma unroll
  for (int off = 1; off < 64; off <<= 1) mx = fmaxf(mx, __shfl_xor(mx, off));
  float s = 0.f;
#pragma unroll
  for (int j = 0; j < 8; ++j) {
    f[j] = __expf(f[j] - mx);
    s += f[j];
  }
#pragma unroll
  for (int off = 1; off < 64; off <<= 1) s += __shfl_xor(s, off);
  const float inv = 1.0f / s;
  bf16x8 o;
#pragma unroll
  for (int j = 0; j < 8; ++j) o[j] = (__bf16)(f[j] * inv);
  *(bf16x8*)p = o;
}

// ======================= phase-interleaved GEMM core ======================
// BM=256, BN=128, BK=64, 8 waves (4M x 2N), 64x64 out per wave per acc.
// Per K-tile: 2 phases; per phase: 8 ds_read_b128 + 3 glds(t+2 half) +
// [P1: counted vmcnt(6)] + barrier + lgkmcnt(0) + setprio + 16 MFMA + bar.
// LDS linear, source-granule pre-swizzle (g ^ row&7) == ds_read swizzle.

#define LOADFRAGS(cb, kk)                                                     \
  {                                                                           \
    const __bf16* As_ = &ldsA[cb][(warp_m * 64 + fr) * 64];                   \
    const __bf16* Bs_ = &ldsB[cb][(warp_n * 64 + fr) * 64];                   \
    const int pg_ = (((kk)*4 + fq) ^ (fr & 7)) * 8;                           \
    _Pragma("unroll") for (int m = 0; m < 4; ++m)                             \
        af[m] = *(const bf16x8*)(As_ + m * 16 * 64 + pg_);                    \
    _Pragma("unroll") for (int n = 0; n < 4; ++n)                             \
        bfv[n] = *(const bf16x8*)(Bs_ + n * 16 * 64 + pg_);                   \
  }

#define MFMA16(ACC)                                                           \
  {                                                                           \
    __builtin_amdgcn_s_barrier();                                             \
    asm volatile("s_waitcnt lgkmcnt(0)" ::: "memory");                        \
    __builtin_amdgcn_s_setprio(1);                                            \
    _Pragma("unroll") for (int m = 0; m < 4; ++m)                             \
        _Pragma("unroll") for (int n = 0; n < 4; ++n)                         \
            ACC[m][n] = __builtin_amdgcn_mfma_f32_16x16x32_bf16(              \
                af[m], bfv[n], ACC[m][n], 0, 0, 0);                           \
    __builtin_amdgcn_s_setprio(0);                                            \
    __builtin_amdgcn_s_barrier();                                             \
  }

#define WAIT6 asm volatile("s_waitcnt vmcnt(6)" ::: "memory")
#define WAIT0 asm volatile("s_waitcnt vmcnt(0)" ::: "memory")

// ---------------- GEMM1: S1 = xb @ mbb^T, K=1024, out bf16 ---------------
__global__ __launch_bounds__(512, 2) void gemm_scores_kernel(
    const __bf16* __restrict__ xb, const __bf16* __restrict__ mbb,
    __bf16* __restrict__ s1) {
  __shared__ __align__(16) __bf16 ldsA[3][256 * 64];
  __shared__ __align__(16) __bf16 ldsB[3][128 * 64];
  const int tid = threadIdx.x;
  const int lane = tid & 63;
  const int wave = tid >> 6;
  const int bid = blockIdx.x;            // 256 blocks
  const int xcd = bid & 7;
  const int idx = bid >> 3;              // 0..31
  const int bm = xcd * 8 + (idx & 7);    // 0..63
  const int bn = idx >> 3;               // 0..3
  const int row0 = bm * 256;
  const int col0 = bn * 128;
  const int warp_m = wave >> 1;
  const int warp_n = wave & 1;
  const int srow = lane >> 3;
  const int sgc = (lane & 7) ^ srow;
  const int wv32 = wave * 32;
  const int wv16 = wave * 16;
  const int fr = lane & 15;
  const int fq = lane >> 4;

  const __bf16* aS = xb + (size_t)(row0 + wv32 + srow) * EMBED + sgc * 8;
  const __bf16* bS = mbb + (size_t)(col0 + wv16 + srow) * EMBED + sgc * 8;

#define STAGE_S1(vt, buf)                                                     \
  {                                                                           \
    const int k0_ = (vt)*64;                                                  \
    _Pragma("unroll") for (int c = 0; c < 2; ++c)                             \
        GLDS(aS + (size_t)c * 8 * EMBED + k0_, &ldsA[buf][(wv32 + c * 8) * 64]); \
    GLDS(bS + k0_, &ldsB[buf][wv16 * 64]);                                    \
  }
#define STAGE_S2(vt, buf)                                                     \
  {                                                                           \
    const int k0_ = (vt)*64;                                                  \
    _Pragma("unroll") for (int c = 2; c < 4; ++c)                             \
        GLDS(aS + (size_t)c * 8 * EMBED + k0_, &ldsA[buf][(wv32 + c * 8) * 64]); \
    GLDS(bS + (size_t)8 * EMBED + k0_, &ldsB[buf][(wv16 + 8) * 64]);          \
  }

  f32x4 acc[4][4];
#pragma unroll
  for (int m = 0; m < 4; ++m)
#pragma unroll
    for (int n = 0; n < 4; ++n) acc[m][n] = (f32x4){0.f, 0.f, 0.f, 0.f};
  bf16x8 af[4], bfv[4];

  STAGE_S1(0, 0); STAGE_S2(0, 0);
  STAGE_S1(1, 1); STAGE_S2(1, 1);
  WAIT6;
  __builtin_amdgcn_s_barrier();

  const int NT = 16;
  for (int vt = 0; vt < NT; ++vt) {
    const int cb = vt % 3;
    const int nb = (vt + 2) % 3;
    // P0
    LOADFRAGS(cb, 0);
    if (vt + 2 < NT) STAGE_S1(vt + 2, nb);
    MFMA16(acc);
    // P1
    LOADFRAGS(cb, 1);
    if (vt + 2 < NT) STAGE_S2(vt + 2, nb);
    if (vt < NT - 2) { WAIT6; } else if (vt == NT - 2) { WAIT0; }
    MFMA16(acc);
  }
#undef STAGE_S1
#undef STAGE_S2

#pragma unroll
  for (int n = 0; n < 4; ++n) {
    const int col = col0 + warp_n * 64 + n * 16 + fr;
#pragma unroll
    for (int m = 0; m < 4; ++m)
#pragma unroll
      for (int j = 0; j < 4; ++j) {
        const int row = row0 + warp_m * 64 + m * 16 + fq * 4 + j;
        s1[(size_t)row * WINDOW + col] = (__bf16)acc[m][n][j];
      }
  }
}

// ---------------- fused dual GEMM + blend --------------------------------
__global__ __launch_bounds__(512, 2) void dual_fused_kernel(
    const __bf16* __restrict__ s1, const __bf16* __restrict__ xb,
    const __bf16* __restrict__ mbt, const __bf16* __restrict__ gwb,
    const float* __restrict__ gb, float* __restrict__ out) {
  __shared__ __align__(16) __bf16 ldsA[3][256 * 64];
  __shared__ __align__(16) __bf16 ldsB[3][128 * 64];
  const int tid = threadIdx.x;
  const int lane = tid & 63;
  const int wave = tid >> 6;
  const int bid = blockIdx.x;               // 512 blocks
  const int xcd = bid & 7;
  const int idx = bid >> 3;                 // 0..63
  const int bm = xcd * 8 + (idx & 7);       // 0..63
  const int bn = idx >> 3;                  // 0..7
  const int row0 = bm * 256;
  const int col0 = bn * 128;
  const int warp_m = wave >> 1;
  const int warp_n = wave & 1;
  const int srow = lane >> 3;
  const int sgc = (lane & 7) ^ srow;
  const int wv32 = wave * 32;
  const int wv16 = wave * 16;
  const int fr = lane & 15;
  const int fq = lane >> 4;

  const __bf16* aR = s1 + (size_t)(row0 + wv32 + srow) * WINDOW + sgc * 8;
  const __bf16* bR = mbt + (size_t)(col0 + wv16 + srow) * WINDOW + sgc * 8;
  const __bf16* aG = xb + (size_t)(row0 + wv32 + srow) * EMBED + sgc * 8;
  const __bf16* bG = gwb + (size_t)(col0 + wv16 + srow) * EMBED + sgc * 8;

#define STAGE_D1(vt, buf)                                                     \
  {                                                                           \
    if ((vt) < 8) {                                                           \
      const int k0_ = (vt)*64;                                                \
      _Pragma("unroll") for (int c = 0; c < 2; ++c)                           \
          GLDS(aR + (size_t)c * 8 * WINDOW + k0_,                             \
               &ldsA[buf][(wv32 + c * 8) * 64]);                              \
      GLDS(bR + k0_, &ldsB[buf][wv16 * 64]);                                  \
    } else {                                                                  \
      const int k0_ = ((vt)-8) * 64;                                          \
      _Pragma("unroll") for (int c = 0; c < 2; ++c)                           \
          GLDS(aG + (size_t)c * 8 * EMBED + k0_,                              \
               &ldsA[buf][(wv32 + c * 8) * 64]);                              \
      GLDS(bG + k0_, &ldsB[buf][wv16 * 64]);                                  \
    }                                                                         \
  }
#define STAGE_D2(vt, buf)                                                     \
  {                                                                           \
    if ((vt) < 8) {                                                           \
      const int k0_ = (vt)*64;                                                \
      _Pragma("unroll") for (int c = 2; c < 4; ++c)                           \
          GLDS(aR + (size_t)c * 8 * WINDOW + k0_,                             \
               &ldsA[buf][(wv32 + c * 8) * 64]);                              \
      GLDS(bR + (size_t)8 * WINDOW + k0_, &ldsB[buf][(wv16 + 8) * 64]);       \
    } else {                                                                  \
      const int k0_ = ((vt)-8) * 64;                                          \
      _Pragma("unroll") for (int c = 2; c < 4; ++c)                           \
          GLDS(aG + (size_t)c * 8 * EMBED + k0_,                              \
               &ldsA[buf][(wv32 + c * 8) * 64]);                              \
      GLDS(bG + (size_t)8 * EMBED + k0_, &ldsB[buf][(wv16 + 8) * 64]);        \
    }                                                                         \
  }

  f32x4 accr[4][4], accg[4][4];
#pragma unroll
  for (int m = 0; m < 4; ++m)
#pragma unroll
    for (int n = 0; n < 4; ++n) {
      accr[m][n] = (f32x4){0.f, 0.f, 0.f, 0.f};
      accg[m][n] = (f32x4){0.f, 0.f, 0.f, 0.f};
    }
  bf16x8 af[4], bfv[4];

  STAGE_D1(0, 0); STAGE_D2(0, 0);
  STAGE_D1(1, 1); STAGE_D2(1, 1);
  WAIT6;
  __builtin_amdgcn_s_barrier();

  const int NT = 24;
  // retrieved phase: vt 0..7
  for (int vt = 0; vt < 8; ++vt) {
    const int cb = vt % 3;
    const int nb = (vt + 2) % 3;
    LOADFRAGS(cb, 0);
    STAGE_D1(vt + 2, nb);
    MFMA16(accr);
    LOADFRAGS(cb, 1);
    STAGE_D2(vt + 2, nb);
    WAIT6;
    MFMA16(accr);
  }
  // gate phase: vt 8..23
  for (int vt = 8; vt < NT; ++vt) {
    const int cb = vt % 3;
    const int nb = (vt + 2) % 3;
    LOADFRAGS(cb, 0);
    if (vt + 2 < NT) STAGE_D1(vt + 2, nb);
    MFMA16(accg);
    LOADFRAGS(cb, 1);
    if (vt + 2 < NT) STAGE_D2(vt + 2, nb);
    if (vt < NT - 2) { WAIT6; } else if (vt == NT - 2) { WAIT0; }
    MFMA16(accg);
  }
#undef STAGE_D1
#undef STAGE_D2

  // epilogue: g = sigmoid(accg + gb); out = g*x + (1-g)*accr
#pragma unroll
  for (int n = 0; n < 4; ++n) {
    const int col = col0 + warp_n * 64 + n * 16 + fr;
    const float bias = gb[col];
#pragma unroll
    for (int m = 0; m < 4; ++m) {
#pragma unroll
      for (int j = 0; j < 4; ++j) {
        const int row = row0 + warp_m * 64 + m * 16 + fq * 4 + j;
        const size_t o = (size_t)row * EMBED + col;
        const float g = 1.0f / (1.0f + __expf(-(accg[m][n][j] + bias)));
        const float xv = (float)xb[o];
        out[o] = g * xv + (1.0f - g) * accr[m][n][j];
      }
    }
  }
}

extern "C" void kernel_launch(void* const* d_in, const int* in_sizes, int n_in,
                              void* d_out, int out_size, void* d_ws,
                              size_t ws_size, hipStream_t stream) {
  const float* x = (const float*)d_in[0];
  const float* mb = (const float*)d_in[1];
  const float* gw = (const float*)d_in[2];
  const float* gb = (const float*)d_in[3];
  float* out = (float*)d_out;

  char* ws = (char*)d_ws;
  __bf16* xb = (__bf16*)(ws);                   // 16384*1024*2 = 33,554,432
  __bf16* mbb = (__bf16*)(ws + 33554432);       // 512*1024*2  =  1,048,576
  __bf16* mbt = (__bf16*)(ws + 34603008);       // 1024*512*2  =  1,048,576
  __bf16* gwb = (__bf16*)(ws + 35651584);       // 1024*1024*2 =  2,097,152
  __bf16* s1 = (__bf16*)(ws + 37748736);        // 16384*512*2 = 16,777,216
  // total 54,525,952 bytes

  cast_bf16_kernel<<<8192, 256, 0, stream>>>(x, xb, 2097152);
  cast_bf16_kernel<<<256, 256, 0, stream>>>(mb, mbb, 65536);
  cast_bf16_kernel<<<512, 256, 0, stream>>>(gw, gwb, 131072);
  transpose_mb_kernel<<<2048, 256, 0, stream>>>(mb, mbt);
  gemm_scores_kernel<<<256, 512, 0, stream>>>(xb, mbb, s1);
  softmax_kernel<<<4096, 256, 0, stream>>>(s1);
  dual_fused_kernel<<<512, 512, 0, stream>>>(s1, xb, mbt, gwb, gb, out);
}